// Round 4
// baseline (2264.456 us; speedup 1.0000x reference)
//
#include <hip/hip_runtime.h>
#include <math.h>

#define NB  1024
#define NN  256
#define NF  4
#define NK  3
#define BIG 32
#define HID 2
#define BN_EPS 1e-5f
#define FLT_BIG 3.402823466e38f

typedef float f32x16 __attribute__((ext_vector_type(16)));

static __device__ __forceinline__ f32x16 splat16(float s) {
    f32x16 v;
#pragma unroll
    for (int k = 0; k < 16; ++k) v[k] = s;
    return v;
}

static __device__ __forceinline__ f32x16 relu16(f32x16 v) {
    return __builtin_elementwise_max(v, splat16(0.0f));
}

// uniform-address LDS read: broadcast ds_read_b128 x4, conflict-free
static __device__ __forceinline__ f32x16 ldlds16(const float* p) {
    return *(const f32x16*)p;
}

// ---------------------------------------------------------------------------
// Kernel 0: zero the BN-stat accumulator (8 doubles in d_ws)
// ---------------------------------------------------------------------------
__global__ void k_zero_ws(double* ws) {
    if (threadIdx.x < 8) ws[threadIdx.x] = 0.0;
}

// ---------------------------------------------------------------------------
// Kernel 1: BatchNorm statistics (fp64 partials -> 8 double atomics)
// ---------------------------------------------------------------------------
__global__ __launch_bounds__(256) void k_bn_reduce(const float4* __restrict__ x,
                                                   double* __restrict__ ws) {
    int tid = blockIdx.x * 256 + threadIdx.x;
    double s[8] = {0, 0, 0, 0, 0, 0, 0, 0};
    for (int r = tid; r < NB * NN; r += 256 * 256) {
        float4 v = x[r];
        s[0] += v.x; s[1] += v.y; s[2] += v.z; s[3] += v.w;
        s[4] += (double)v.x * v.x; s[5] += (double)v.y * v.y;
        s[6] += (double)v.z * v.z; s[7] += (double)v.w * v.w;
    }
#pragma unroll
    for (int off = 32; off > 0; off >>= 1) {
#pragma unroll
        for (int i = 0; i < 8; i++) s[i] += __shfl_down(s[i], off);
    }
    __shared__ double red[4][8];
    int w = threadIdx.x >> 6, lane = threadIdx.x & 63;
    if (lane == 0) {
#pragma unroll
        for (int i = 0; i < 8; i++) red[w][i] = s[i];
    }
    __syncthreads();
    if (threadIdx.x == 0) {
#pragma unroll
        for (int i = 0; i < 8; i++) {
            double t = red[0][i] + red[1][i] + red[2][i] + red[3][i];
            atomicAdd(&ws[i], t);
        }
    }
}

// ---------------------------------------------------------------------------
// Kernel 2: fused BN + encoder conv + decoder conv. One block per graph.
// Weights staged to LDS (16B-aligned segments), read as uniform broadcast
// ds_read_b128 -> VGPRs; hidden state in f32x16 register accumulators.
// kNN path is bit-identical to the passing round-2 kernel.
// ---------------------------------------------------------------------------

// padded LDS segment offsets (floats, all multiples of 16)
#define O_EW1 0       // 256
#define O_EB1 256     // 32
#define O_EW2 288     // 1024
#define O_EB2 1312    // 32
#define O_EW3 1344    // 64
#define O_EB3 1408    // 2  (pad to 16)
#define O_DW1 1424    // 128
#define O_DB1 1552    // 32
#define O_DW2 1584    // 1024
#define O_DB2 2608    // 32
#define O_DW3 2640    // 128
#define O_DB3 2768    // 4  (pad)
#define SW_SZ 2784

__global__ __launch_bounds__(256, 4) void k_edgenet(
    const float*  __restrict__ x,
    const float*  __restrict__ gmm, const float* __restrict__ bta,
    const float*  __restrict__ ew1, const float* __restrict__ eb1,
    const float*  __restrict__ ew2, const float* __restrict__ eb2,
    const float*  __restrict__ ew3, const float* __restrict__ eb3,
    const float*  __restrict__ dw1, const float* __restrict__ db1,
    const float*  __restrict__ dw2, const float* __restrict__ db2,
    const float*  __restrict__ dw3, const float* __restrict__ db3,
    const double* __restrict__ bnstat,
    float*        __restrict__ out)
{
    __shared__ float s_h[NN][NF];
    __shared__ float s_sq[NN];
    __shared__ float s_he[NN][HID];
    __shared__ float s_sq2[NN];
    __shared__ float sw[SW_SZ];

    const int n = threadIdx.x;
    const int b = blockIdx.x;

    // ---- cooperative weight staging into LDS ----
    sw[O_EW1 + n] = ew1[n];
    if (n < 32)  sw[O_EB1 + n] = eb1[n];
    for (int i = n; i < 1024; i += 256) sw[O_EW2 + i] = ew2[i];
    if (n < 32)  sw[O_EB2 + n] = eb2[n];
    if (n < 64)  sw[O_EW3 + n] = ew3[n];
    if (n < 2)   sw[O_EB3 + n] = eb3[n];
    if (n < 128) sw[O_DW1 + n] = dw1[n];
    if (n < 32)  sw[O_DB1 + n] = db1[n];
    for (int i = n; i < 1024; i += 256) sw[O_DW2 + i] = dw2[i];
    if (n < 32)  sw[O_DB2 + n] = db2[n];
    if (n < 128) sw[O_DW3 + n] = dw3[n];
    if (n < 4)   sw[O_DB3 + n] = db3[n];

    // ---- BN parameters (uniform) ----
    const double cnt = (double)(NB * NN);
    float mu[NF], rstd[NF];
#pragma unroll
    for (int f = 0; f < NF; f++) {
        double m   = bnstat[f] / cnt;
        double var = bnstat[4 + f] / cnt - m * m;
        mu[f]   = (float)m;
        rstd[f] = 1.0f / sqrtf((float)var + BN_EPS);
    }

    float4 xv = ((const float4*)x)[b * NN + n];
    float h0 = (xv.x - mu[0]) * rstd[0] * gmm[0] + bta[0];
    float h1 = (xv.y - mu[1]) * rstd[1] * gmm[1] + bta[1];
    float h2 = (xv.z - mu[2]) * rstd[2] * gmm[2] + bta[2];
    float h3 = (xv.w - mu[3]) * rstd[3] * gmm[3] + bta[3];
    s_h[n][0] = h0; s_h[n][1] = h1; s_h[n][2] = h2; s_h[n][3] = h3;
    float sq = h0 * h0 + h1 * h1 + h2 * h2 + h3 * h3;
    s_sq[n] = sq;
    __syncthreads();

    // ---------------- encoder kNN (bit-identical to round 2) ---------------
    float d0 = FLT_BIG, d1 = FLT_BIG, d2 = FLT_BIG;
    int   i0 = 0, i1 = 0, i2 = 0;
    for (int m = 0; m < NN; ++m) {
        float a0 = s_h[m][0], a1 = s_h[m][1], a2 = s_h[m][2], a3 = s_h[m][3];
        float dot = h0 * a0 + h1 * a1 + h2 * a2 + h3 * a3;
        float d = (sq + s_sq[m]) - 2.0f * dot;
        bool c0 = d < d0, c1 = d < d1, c2 = d < d2;
        d2 = c1 ? d1 : (c2 ? d : d2);  i2 = c1 ? i1 : (c2 ? m : i2);
        d1 = c0 ? d0 : (c1 ? d : d1);  i1 = c0 ? i0 : (c1 ? m : i1);
        d0 = c0 ? d  : d0;             i0 = c0 ? m  : i0;
    }

    // ---------------- encoder messages + mean ------------------------------
    // hoisted x_i half of layer 1 (same fmac order as full computation)
    f32x16 c1a = ldlds16(sw + O_EB1), c1b = ldlds16(sw + O_EB1 + 16);
    {
        float hs[4] = {h0, h1, h2, h3};
#pragma unroll
        for (int i = 0; i < 4; i++) {
            f32x16 s = splat16(hs[i]);
            c1a += s * ldlds16(sw + O_EW1 + i * BIG);
            c1b += s * ldlds16(sw + O_EW1 + i * BIG + 16);
        }
    }
    float ms0 = 0.0f, ms1 = 0.0f;
#pragma unroll 1
    for (int k = 0; k < NK; ++k) {
        int j = (k == 0) ? i0 : ((k == 1) ? i1 : i2);
        // layer 1: [8] -> [32]; delta part only (x_i part hoisted)
        f32x16 h1a = c1a, h1b = c1b;
        if (j != n) {   // delta == 0 when j==n: contributes exactly +0
            float e4 = s_h[j][0] - h0, e5 = s_h[j][1] - h1;
            float e6 = s_h[j][2] - h2, e7 = s_h[j][3] - h3;
            float es[4] = {e4, e5, e6, e7};
#pragma unroll
            for (int i = 0; i < 4; i++) {
                f32x16 s = splat16(es[i]);
                h1a += s * ldlds16(sw + O_EW1 + (4 + i) * BIG);
                h1b += s * ldlds16(sw + O_EW1 + (4 + i) * BIG + 16);
            }
        }
        h1a = relu16(h1a); h1b = relu16(h1b);

        // layer 2: [32] -> [32]
        f32x16 h2a = ldlds16(sw + O_EB2), h2b = ldlds16(sw + O_EB2 + 16);
#pragma unroll
        for (int i = 0; i < 16; i++) {
            f32x16 s = splat16(h1a[i]);
            h2a += s * ldlds16(sw + O_EW2 + i * BIG);
            h2b += s * ldlds16(sw + O_EW2 + i * BIG + 16);
        }
#pragma unroll
        for (int i = 0; i < 16; i++) {
            f32x16 s = splat16(h1b[i]);
            h2a += s * ldlds16(sw + O_EW2 + (16 + i) * BIG);
            h2b += s * ldlds16(sw + O_EW2 + (16 + i) * BIG + 16);
        }
        h2a = relu16(h2a); h2b = relu16(h2b);

        // layer 3: [32] -> [2], final relu. ew3 is [32][2] row-major.
        float o0 = sw[O_EB3], o1 = sw[O_EB3 + 1];
#pragma unroll
        for (int c = 0; c < 2; c++) {
            f32x16 w = ldlds16(sw + O_EW3 + c * 16);   // rows 8c..8c+7
#pragma unroll
            for (int r = 0; r < 8; r++) {
                o0 += h2a[c * 8 + r] * w[2 * r];
                o1 += h2a[c * 8 + r] * w[2 * r + 1];
            }
        }
#pragma unroll
        for (int c = 0; c < 2; c++) {
            f32x16 w = ldlds16(sw + O_EW3 + 32 + c * 16);
#pragma unroll
            for (int r = 0; r < 8; r++) {
                o0 += h2b[c * 8 + r] * w[2 * r];
                o1 += h2b[c * 8 + r] * w[2 * r + 1];
            }
        }
        ms0 += fmaxf(o0, 0.0f);
        ms1 += fmaxf(o1, 0.0f);
    }
    float he0 = ms0 / 3.0f, he1 = ms1 / 3.0f;
    s_he[n][0] = he0; s_he[n][1] = he1;
    float sqe = he0 * he0 + he1 * he1;
    s_sq2[n] = sqe;
    __syncthreads();

    // ---------------- decoder kNN (bit-identical to round 2) ---------------
    d0 = FLT_BIG; d1 = FLT_BIG; d2 = FLT_BIG;
    i0 = 0; i1 = 0; i2 = 0;
    for (int m = 0; m < NN; ++m) {
        float a0 = s_he[m][0], a1 = s_he[m][1];
        float dot = he0 * a0 + he1 * a1;
        float d = (sqe + s_sq2[m]) - 2.0f * dot;
        bool c0 = d < d0, c1 = d < d1, c2 = d < d2;
        d2 = c1 ? d1 : (c2 ? d : d2);  i2 = c1 ? i1 : (c2 ? m : i2);
        d1 = c0 ? d0 : (c1 ? d : d1);  i1 = c0 ? i0 : (c1 ? m : i1);
        d0 = c0 ? d  : d0;             i0 = c0 ? m  : i0;
    }

    // ---------------- decoder messages + mean ------------------------------
    // hoisted he_i half of layer 1
    f32x16 g1a = ldlds16(sw + O_DB1), g1b = ldlds16(sw + O_DB1 + 16);
    {
        float hs[2] = {he0, he1};
#pragma unroll
        for (int i = 0; i < 2; i++) {
            f32x16 s = splat16(hs[i]);
            g1a += s * ldlds16(sw + O_DW1 + i * BIG);
            g1b += s * ldlds16(sw + O_DW1 + i * BIG + 16);
        }
    }
    float o0s = 0.0f, o1s = 0.0f, o2s = 0.0f, o3s = 0.0f;
#pragma unroll 1
    for (int k = 0; k < NK; ++k) {
        int j = (k == 0) ? i0 : ((k == 1) ? i1 : i2);
        float e2 = s_he[j][0] - he0, e3 = s_he[j][1] - he1;

        // layer 1: delta part (2 rows)
        f32x16 h1a = g1a, h1b = g1b;
        {
            f32x16 s = splat16(e2);
            h1a += s * ldlds16(sw + O_DW1 + 2 * BIG);
            h1b += s * ldlds16(sw + O_DW1 + 2 * BIG + 16);
            s = splat16(e3);
            h1a += s * ldlds16(sw + O_DW1 + 3 * BIG);
            h1b += s * ldlds16(sw + O_DW1 + 3 * BIG + 16);
        }
        h1a = relu16(h1a); h1b = relu16(h1b);

        // layer 2: [32] -> [32]
        f32x16 h2a = ldlds16(sw + O_DB2), h2b = ldlds16(sw + O_DB2 + 16);
#pragma unroll
        for (int i = 0; i < 16; i++) {
            f32x16 s = splat16(h1a[i]);
            h2a += s * ldlds16(sw + O_DW2 + i * BIG);
            h2b += s * ldlds16(sw + O_DW2 + i * BIG + 16);
        }
#pragma unroll
        for (int i = 0; i < 16; i++) {
            f32x16 s = splat16(h1b[i]);
            h2a += s * ldlds16(sw + O_DW2 + (16 + i) * BIG);
            h2b += s * ldlds16(sw + O_DW2 + (16 + i) * BIG + 16);
        }
        h2a = relu16(h2a); h2b = relu16(h2b);

        // layer 3: [32] -> [4], no final relu. dw3 is [32][4] row-major.
        float o0 = sw[O_DB3], o1 = sw[O_DB3 + 1];
        float o2 = sw[O_DB3 + 2], o3 = sw[O_DB3 + 3];
#pragma unroll
        for (int c = 0; c < 4; c++) {
            f32x16 w = ldlds16(sw + O_DW3 + c * 16);   // rows 4c..4c+3
#pragma unroll
            for (int r = 0; r < 4; r++) {
                float s = h2a[c * 4 + r];
                o0 += s * w[4 * r];     o1 += s * w[4 * r + 1];
                o2 += s * w[4 * r + 2]; o3 += s * w[4 * r + 3];
            }
        }
#pragma unroll
        for (int c = 0; c < 4; c++) {
            f32x16 w = ldlds16(sw + O_DW3 + 64 + c * 16);
#pragma unroll
            for (int r = 0; r < 4; r++) {
                float s = h2b[c * 4 + r];
                o0 += s * w[4 * r];     o1 += s * w[4 * r + 1];
                o2 += s * w[4 * r + 2]; o3 += s * w[4 * r + 3];
            }
        }
        o0s += o0; o1s += o1; o2s += o2; o3s += o3;
    }
    float4 ov;
    ov.x = o0s / 3.0f; ov.y = o1s / 3.0f;
    ov.z = o2s / 3.0f; ov.w = o3s / 3.0f;
    ((float4*)out)[b * NN + n] = ov;
}

// ---------------------------------------------------------------------------
extern "C" void kernel_launch(void* const* d_in, const int* in_sizes, int n_in,
                              void* d_out, int out_size, void* d_ws, size_t ws_size,
                              hipStream_t stream) {
    const float* x   = (const float*)d_in[0];
    const float* gmm = (const float*)d_in[1];
    const float* bta = (const float*)d_in[2];
    const float* ew1 = (const float*)d_in[3];
    const float* eb1 = (const float*)d_in[4];
    const float* ew2 = (const float*)d_in[5];
    const float* eb2 = (const float*)d_in[6];
    const float* ew3 = (const float*)d_in[7];
    const float* eb3 = (const float*)d_in[8];
    const float* dw1 = (const float*)d_in[9];
    const float* db1 = (const float*)d_in[10];
    const float* dw2 = (const float*)d_in[11];
    const float* db2 = (const float*)d_in[12];
    const float* dw3 = (const float*)d_in[13];
    const float* db3 = (const float*)d_in[14];
    double* ws = (double*)d_ws;
    float* out = (float*)d_out;

    hipLaunchKernelGGL(k_zero_ws, dim3(1), dim3(64), 0, stream, ws);
    hipLaunchKernelGGL(k_bn_reduce, dim3(256), dim3(256), 0, stream,
                       (const float4*)x, ws);
    hipLaunchKernelGGL(k_edgenet, dim3(NB), dim3(256), 0, stream,
                       x, gmm, bta, ew1, eb1, ew2, eb2, ew3, eb3,
                       dw1, db1, dw2, db2, dw3, db3, ws, out);
}